// Round 1
// baseline (5873.679 us; speedup 1.0000x reference)
//
#include <hip/hip_runtime.h>
#include <hip/hip_fp16.h>

typedef unsigned int u32;

#define TT 2048
#define HD 256
#define G4 1024
#define NT 16
#define START_TAG 14
#define STOP_TAG 15
#define NEGV (-10000.0f)

typedef _Float16 half2v __attribute__((ext_vector_type(2)));

__device__ __forceinline__ float fdot2u(u32 a, u32 b, float c) {
    return __builtin_amdgcn_fdot2(__builtin_bit_cast(half2v, a),
                                  __builtin_bit_cast(half2v, b), c, false);
}
__device__ __forceinline__ float sigmf_(float x) { return 1.0f / (1.0f + __expf(-x)); }
__device__ __forceinline__ float tanhf_(float x) {
    float e = __expf(-2.0f * fabsf(x));
    return copysignf((1.0f - e) / (1.0f + e), x);
}

// K0: pack w_hh to f16 pairs. Register part [dir][1024][96], LDS part transposed [dir][32][1024].
__global__ __launch_bounds__(128) void pack_whh(const float* whh_f, const float* whh_b,
                                                u32* wregp, u32* wldsp) {
    int row = blockIdx.x, dir = blockIdx.y, k = threadIdx.x;
    const float* w = (dir ? whh_b : whh_f) + (size_t)row * HD;
    if (k < 96) {
        u32 lo = __half_as_ushort(__float2half(w[2 * k]));
        u32 hi = __half_as_ushort(__float2half(w[2 * k + 1]));
        wregp[((size_t)dir * G4 + row) * 96 + k] = lo | (hi << 16);
    } else {
        int q = k - 96;
        u32 lo = __half_as_ushort(__float2half(w[192 + 2 * q]));
        u32 hi = __half_as_ushort(__float2half(w[193 + 2 * q]));
        wldsp[((size_t)dir * 32 + q) * G4 + row] = lo | (hi << 16);
    }
}

// K1: G[dir][t][r] = dot(embed[sent[t or T-1-t]], w_ih[r]) + b[r]   (f32 exact)
__global__ __launch_bounds__(256) void input_gemm(const int* sent, const float* embed,
                                                  const float* wih_f, const float* b_f,
                                                  const float* wih_b, const float* b_b,
                                                  float* G) {
    __shared__ float X[32][HD];   // 32KB
    __shared__ int rows[32];
    int tid = threadIdx.x;
    int dir = blockIdx.z;
    int t0 = blockIdx.x * 32;
    if (tid < 32) {
        int tg = t0 + tid;
        rows[tid] = sent[dir ? (TT - 1 - tg) : tg];
    }
    __syncthreads();
    for (int i = 0; i < 32; i++) X[i][tid] = embed[(size_t)rows[i] * HD + tid];
    __syncthreads();
    int r = blockIdx.y * 256 + tid;
    const float* wrow = (dir ? wih_b : wih_f) + (size_t)r * HD;
    float acc[32];
#pragma unroll
    for (int i = 0; i < 32; i++) acc[i] = 0.0f;
    for (int kc = 0; kc < HD / 4; kc++) {
        float4 w4 = ((const float4*)wrow)[kc];
#pragma unroll
        for (int i = 0; i < 32; i++) {
            float4 x4 = *((const float4*)&X[i][kc * 4]);
            acc[i] += w4.x * x4.x + w4.y * x4.y + w4.z * x4.z + w4.w * x4.w;
        }
    }
    float bias = (dir ? b_b : b_f)[r];
    for (int i = 0; i < 32; i++)
        G[((size_t)dir * TT + t0 + i) * G4 + r] = acc[i] + bias;
}

// K2: persistent per-direction LSTM recurrence. 1024 threads = 1024 gate rows.
// W_hh f16: 96 u32 (192 f16) per thread in VGPRs + [32][1024] u32 in LDS (conflict-free b32 reads).
__global__ __launch_bounds__(1024) void lstm_rec(const u32* wregp, const u32* wldsp,
                                                 const float* G, const float* h0,
                                                 const float* c0, float* H) {
    __shared__ u32 Wl[32 * G4];            // 128KB
    __shared__ float gates[G4];            // 4KB
    __shared__ __align__(16) u32 h2[128];  // 256 f16 of h
    int tid = threadIdx.x;
    int dir = blockIdx.x;
    for (int q = 0; q < 32; q++)
        Wl[q * G4 + tid] = wldsp[((size_t)dir * 32 + q) * G4 + tid];
    u32 wreg[96];
    const uint4* wp = (const uint4*)(wregp + ((size_t)dir * G4 + tid) * 96);
#pragma unroll
    for (int i = 0; i < 24; i++) {
        uint4 v = wp[i];
        wreg[4 * i] = v.x; wreg[4 * i + 1] = v.y; wreg[4 * i + 2] = v.z; wreg[4 * i + 3] = v.w;
    }
    float cst = 0.0f;
    if (tid < HD) {
        cst = c0[dir * HD + tid];
        ((unsigned short*)h2)[tid] = __half_as_ushort(__float2half(h0[dir * HD + tid]));
    }
    __syncthreads();
    const float* Gd = G + (size_t)dir * TT * G4;
    float* Hd = H + (size_t)dir * TT * HD;
    for (int t = 0; t < TT; t++) {
        float gin = Gd[(size_t)t * G4 + tid];   // issued early, used after dots
        float acc = 0.0f;
#pragma unroll
        for (int p = 0; p < 96; p += 4) {
            uint4 h4 = *((const uint4*)&h2[p]);   // wave-uniform broadcast read
            acc = fdot2u(wreg[p + 0], h4.x, acc);
            acc = fdot2u(wreg[p + 1], h4.y, acc);
            acc = fdot2u(wreg[p + 2], h4.z, acc);
            acc = fdot2u(wreg[p + 3], h4.w, acc);
        }
#pragma unroll
        for (int q = 0; q < 32; q += 4) {
            uint4 h4 = *((const uint4*)&h2[96 + q]);
            acc = fdot2u(Wl[(q + 0) * G4 + tid], h4.x, acc);
            acc = fdot2u(Wl[(q + 1) * G4 + tid], h4.y, acc);
            acc = fdot2u(Wl[(q + 2) * G4 + tid], h4.z, acc);
            acc = fdot2u(Wl[(q + 3) * G4 + tid], h4.w, acc);
        }
        gates[tid] = acc + gin;
        __syncthreads();
        if (tid < HD) {
            float gi = gates[tid], gf = gates[tid + 256];
            float gg = gates[tid + 512], go = gates[tid + 768];
            cst = sigmf_(gf) * cst + sigmf_(gi) * tanhf_(gg);
            float h = sigmf_(go) * tanhf_(cst);
            Hd[(size_t)t * HD + tid] = h;
            ((unsigned short*)h2)[tid] = __half_as_ushort(__float2half(h));
        }
        __syncthreads();
    }
}

// K3: feats[t][n] = hf[t]·w_out[n][0:256] + hb_scan[T-1-t]·w_out[n][256:512] + b_out[n]
__global__ __launch_bounds__(256) void feats_kernel(const float* H, const float* w_out,
                                                    const float* b_out, float* feats) {
    int idx = blockIdx.x * blockDim.x + threadIdx.x;
    int t = idx >> 4, n = idx & 15;
    const float* hf = H + (size_t)t * HD;
    const float* hb = H + ((size_t)TT + (TT - 1 - t)) * HD;
    const float* w = w_out + (size_t)n * (2 * HD);
    float a = b_out[n];
    for (int k = 0; k < HD; k += 4) {
        float4 h4 = *((const float4*)&hf[k]);
        float4 w4 = *((const float4*)&w[k]);
        a += h4.x * w4.x + h4.y * w4.y + h4.z * w4.z + h4.w * w4.w;
    }
    for (int k = 0; k < HD; k += 4) {
        float4 h4 = *((const float4*)&hb[k]);
        float4 w4 = *((const float4*)&w[HD + k]);
        a += h4.x * w4.x + h4.y * w4.y + h4.z * w4.z + h4.w * w4.w;
    }
    feats[(size_t)t * NT + n] = a;
}

// K4: Viterbi + backtrack, single wave. lane = next*4 + prev_quad.
__global__ __launch_bounds__(64) void viterbi_kernel(const float* feats, const float* trans,
                                                     float* out) {
    __shared__ float fvs[NT];
    __shared__ unsigned char bps[TT][NT];   // 32KB
    int lane = threadIdx.x;
    int n = lane >> 2, pg = lane & 3;
    float4 tr4 = *((const float4*)&trans[n * NT + pg * 4]);
    if (lane < NT) fvs[lane] = (lane == START_TAG) ? 0.0f : NEGV;
    __syncthreads();
    for (int t = 0; t < TT; t++) {
        float f0 = fvs[pg * 4 + 0], f1 = fvs[pg * 4 + 1];
        float f2 = fvs[pg * 4 + 2], f3 = fvs[pg * 4 + 3];
        float ft = feats[t * NT + n];
        float v = f0 + tr4.x; int bi = pg * 4;
        float v1 = f1 + tr4.y; if (v1 > v) { v = v1; bi = pg * 4 + 1; }
        float v2 = f2 + tr4.z; if (v2 > v) { v = v2; bi = pg * 4 + 2; }
        float v3 = f3 + tr4.w; if (v3 > v) { v = v3; bi = pg * 4 + 3; }
        // reduce over the 4 prev-quads of this next-tag; first-index tie-break
#pragma unroll
        for (int m = 1; m <= 2; m <<= 1) {
            float ov = __shfl_xor(v, m, 64);
            int ob = __shfl_xor(bi, m, 64);
            if (ov > v || (ov == v && ob < bi)) { v = ov; bi = ob; }
        }
        __syncthreads();
        if (pg == 0) {
            bps[t][n] = (unsigned char)bi;
            fvs[n] = v + ft;
        }
        __syncthreads();
    }
    if (lane == 0) {
        float best = -3.0e38f; int bt = 0;
        for (int p = 0; p < NT; p++) {
            float tv = fvs[p] + trans[STOP_TAG * NT + p];
            if (tv > best) { best = tv; bt = p; }
        }
        out[0] = best;
        int tag = bt;
        out[TT] = (float)tag;                  // path[T-1]
        for (int t = TT - 2; t >= 0; t--) {
            tag = bps[t + 1][tag];
            out[1 + t] = (float)tag;
        }
    }
}

extern "C" void kernel_launch(void* const* d_in, const int* in_sizes, int n_in,
                              void* d_out, int out_size, void* d_ws, size_t ws_size,
                              hipStream_t stream) {
    const int* sent = (const int*)d_in[0];
    const float* embed = (const float*)d_in[1];
    const float* wih_f = (const float*)d_in[2];
    const float* whh_f = (const float*)d_in[3];
    const float* b_f = (const float*)d_in[4];
    const float* wih_b = (const float*)d_in[5];
    const float* whh_b = (const float*)d_in[6];
    const float* b_b = (const float*)d_in[7];
    const float* w_out = (const float*)d_in[8];
    const float* b_out = (const float*)d_in[9];
    const float* trans = (const float*)d_in[10];
    const float* h0 = (const float*)d_in[11];
    const float* c0 = (const float*)d_in[12];
    float* out = (float*)d_out;
    char* ws = (char*)d_ws;

    float* G = (float*)(ws);                               // 2*2048*1024*4 = 16MB
    float* H = (float*)(ws + (size_t)16 * 1024 * 1024);    // 2*2048*256*4  = 4MB
    float* feats = (float*)(ws + (size_t)20 * 1024 * 1024);// 128KB
    u32* wregp = (u32*)(ws + (size_t)21 * 1024 * 1024);    // 768KB
    u32* wldsp = (u32*)(ws + (size_t)22 * 1024 * 1024);    // 256KB

    pack_whh<<<dim3(G4, 2), 128, 0, stream>>>(whh_f, whh_b, wregp, wldsp);
    input_gemm<<<dim3(TT / 32, G4 / 256, 2), 256, 0, stream>>>(sent, embed, wih_f, b_f,
                                                               wih_b, b_b, G);
    lstm_rec<<<dim3(2), 1024, 0, stream>>>(wregp, wldsp, G, h0, c0, H);
    feats_kernel<<<dim3(TT * NT / 256), 256, 0, stream>>>(H, w_out, b_out, feats);
    viterbi_kernel<<<dim3(1), 64, 0, stream>>>(feats, trans, out);
}